// Round 2
// baseline (150.795 us; speedup 1.0000x reference)
//
#include <hip/hip_runtime.h>

// B=32, H=W=128, C_IN=C_OUT=32, 3x3 SAME conv, per-sample hypernet weights
// Wk[b] = (P[b] @ dense_w).reshape(3,3,32,32).
//
// R7 restructure (single-pass conv) — resubmit of R1 (infra failure, source
// audited: no OOB, no barrier divergence, LDS/VGPR budgets legal):
//  - OLD: cvt pass (X f32 -> Xh f16, 100 MB) + conv reading Xh from global.
//    Total HBM ~250 MB vs 139 MB mandatory.
//  - NEW: conv stages its own 8 rows f32->f16 into 64 KB LDS (XOR-swizzled,
//    2-way max bank aliasing = free), A-frags via ds_read_b128. Halo rows
//    (waves 0/7 only) come from f32 global with a 1-tile prefetch.
//  - hyper: 144 blocks x (64 cols x all 32 batches) -> Dw read exactly ONCE
//    (was 8x = 37.7 MB). P via wave-uniform scalar loads, no LDS.
// Traffic: ~158 MB total (X 67 + Y 67 + Dw 4.7 + halo/WB slop).

#define BATCH 32
#define HDIM 128
#define WDIM 128
#define CIN 32
#define COUT 32
#define PDIM 128
#define KCOLS 9216  // 3*3*32*32

typedef _Float16 f16x8 __attribute__((ext_vector_type(8)));
typedef float f32x4 __attribute__((ext_vector_type(4)));

__device__ __forceinline__ f16x8 zero8() {
    f16x8 z;
#pragma unroll
    for (int j = 0; j < 8; ++j) z[j] = (_Float16)0.f;
    return z;
}

// ---------------------------------------------------------------------------
// hyper_gemm: A = P @ dense_w -> f16, swizzled to MFMA B-frag layout
// WB[b][(kc*2 + co>>4)*64 + (ci>>3)*16 + (co&15)]*8 + (ci&7).
// 144 blocks x 256 thr. Block owns 64 columns; wave wv owns batches wv*8..+7.
// Dw column read ONCE (4.7 MB total). P[b][m] is wave-uniform -> scalar loads.
// ---------------------------------------------------------------------------
__global__ __launch_bounds__(256) void hyper_gemm(const float* __restrict__ P,
                                                  const float* __restrict__ Dw,
                                                  unsigned short* __restrict__ WB) {
    const int tid = threadIdx.x;
    const int lane = tid & 63;
    const int col = blockIdx.x * 64 + lane;
    const int b0 = __builtin_amdgcn_readfirstlane((tid >> 6) * 8);
    const float* pb = P + (size_t)b0 * PDIM;  // wave-uniform base -> s_load

    float acc[8];
#pragma unroll
    for (int j = 0; j < 8; ++j) acc[j] = 0.f;

#pragma unroll 2
    for (int mm = 0; mm < PDIM; mm += 16) {
        float d[16];
#pragma unroll
        for (int u = 0; u < 16; ++u) d[u] = Dw[(size_t)(mm + u) * KCOLS + col];
#pragma unroll
        for (int u = 0; u < 16; ++u) {
#pragma unroll
            for (int j = 0; j < 8; ++j) acc[j] += d[u] * pb[j * PDIM + mm + u];
        }
    }

    const int co = col & 31;
    const int k = col >> 5;
    const int kc = k >> 5;
    const int ci = k & 31;
    const int base =
        ((kc * 2 + (co >> 4)) * 64 + (ci >> 3) * 16 + (co & 15)) * 8 + (ci & 7);
#pragma unroll
    for (int j = 0; j < 8; ++j) {
        _Float16 v = (_Float16)acc[j];
        WB[(size_t)(b0 + j) * KCOLS + base] = __builtin_bit_cast(unsigned short, v);
    }
}

// ---------------------------------------------------------------------------
// conv_fused: implicit-GEMM conv, single pass over X.
// Grid 512 (XCD-swizzled: 16 blocks of an image stay on one XCD -> halo +
// WB L2-local). Block = 8 rows x 512 thr (8 waves, wave = one row).
// Stage: 8 own rows f32 -> f16 -> LDS [8][128 px][4 granules of 16B],
//   granule slot = q ^ (px>>1) (write/read use identical mapping; per-tile
//   +1024B step preserves (px>>1)&3 since px steps by 16).
// Compute: per tile t (16 px): per kh trio {3 ds_read_b128 A-frags, 6 MFMA
//   16x16x32_f16}, 8 stores. B-frags (18 x f16x8 = 72 VGPR) loaded once from
//   global WB (L2-resident per image). Waves 0/7 take their out-of-block row
//   from f32 global with a 1-tile prefetch (hal[3]).
// launch_bounds(512,4): cap 128 VGPR so 2 blocks/CU (LDS 64 KB also = 2/CU).
// ---------------------------------------------------------------------------
__device__ __forceinline__ f16x8 halo_ld(const f32x4* __restrict__ gp, int px) {
    const bool ok = (unsigned)px < 128u;
    const int p = ok ? px : 0;
    f32x4 lo = gp[p * 8];
    f32x4 hi = gp[p * 8 + 1];
    f16x8 o;
#pragma unroll
    for (int j = 0; j < 4; ++j) {
        o[j] = (_Float16)lo[j];
        o[4 + j] = (_Float16)hi[j];
    }
    if (!ok) o = zero8();
    return o;
}

__global__ __launch_bounds__(512, 4) void conv_fused(const float* __restrict__ X,
                                                     const unsigned short* __restrict__ WB,
                                                     float* __restrict__ Y) {
    __shared__ f16x8 Xs[8 * 512];  // 64 KB: [row 0..7][px*4 + slot]
    const int tid = threadIdx.x;

    // XCD-aware swizzle: 512 % 8 == 0 -> simple bijective form.
    const int wg = blockIdx.x;
    const int id = (wg & 7) * 64 + (wg >> 3);
    const int b = id >> 4;
    const int hg = id & 15;
    const int r0 = hg * 8;

    const int wave = tid >> 6;
    const int lane = tid & 63;
    const int q = lane >> 4;    // ci octet
    const int m16 = lane & 15;  // pixel within tile

    // ---- B-fragments: direct global -> reg (18.4 KB/image, L2-hot) ----
    f16x8 bf[18];
    {
        const f16x8* wbp = (const f16x8*)(WB + (size_t)b * KCOLS);
#pragma unroll
        for (int i = 0; i < 18; ++i) bf[i] = wbp[i * 64 + lane];
    }

    // ---- stage 8 own rows: f32 load -> f16 -> swizzled LDS ----
    {
        const int px_s = tid >> 2;  // 0..127
        const int q_s = tid & 3;
        const int g_s = px_s * 4 + ((q_s ^ (px_s >> 1)) & 3);
        const float* xsrc =
            X + (((size_t)b * HDIM + r0) * WDIM + px_s) * CIN + q_s * 8;
#pragma unroll
        for (int r = 0; r < 8; ++r) {
            f32x4 lo = *(const f32x4*)(xsrc + (size_t)r * WDIM * CIN);
            f32x4 hi = *(const f32x4*)(xsrc + (size_t)r * WDIM * CIN + 4);
            f16x8 o;
#pragma unroll
            for (int j = 0; j < 4; ++j) {
                o[j] = (_Float16)lo[j];
                o[4 + j] = (_Float16)hi[j];
            }
            Xs[r * 512 + g_s] = o;
        }
    }

    // ---- halo setup (waves 0 and 7 only) ----
    const bool top = (wave == 0);
    const bool bot = (wave == 7);
    const bool gvalid = top ? (hg != 0) : (bot ? (hg != 15) : false);
    const int grow = top ? (r0 - 1) : (r0 + 8);
    const f32x4* gp =
        (const f32x4*)X + ((size_t)b * HDIM + (gvalid ? grow : 0)) * (WDIM * CIN / 4) +
        q * 2;

    f16x8 hal[3];
    if (gvalid) {
#pragma unroll
        for (int kw = 0; kw < 3; ++kw) hal[kw] = halo_ld(gp, m16 + kw - 1);
    } else {
#pragma unroll
        for (int kw = 0; kw < 3; ++kw) hal[kw] = zero8();
    }

    // ---- per-lane LDS byte offsets, base row (wave-1); +kh*8192 at use ----
    int va[3];
#pragma unroll
    for (int kw = 0; kw < 3; ++kw) {
        const int px = m16 + kw - 1;
        const int sl = (q ^ (px >> 1)) & 3;
        va[kw] = (wave - 1) * 8192 + px * 64 + sl * 16;
    }

    __syncthreads();

    const char* xsb = (const char*)Xs;
    const int h = r0 + wave;
    float* ybase = Y + (((size_t)b * HDIM + h) * WDIM + q * 4) * COUT + m16;

#pragma unroll
    for (int t = 0; t < 8; ++t) {
        f32x4 acc0 = {0.f, 0.f, 0.f, 0.f};
        f32x4 acc1 = {0.f, 0.f, 0.f, 0.f};

#pragma unroll
        for (int kh = 0; kh < 3; ++kh) {
            f16x8 a0, a1, a2;
            const bool use_lds =
                (kh == 1) || (kh == 0 && wave != 0) || (kh == 2 && wave != 7);
            if (use_lds) {
                int v0 = va[0] + kh * 8192;
                int v1 = va[1] + kh * 8192;
                int v2 = va[2] + kh * 8192;
                if (t == 0) v0 += (m16 == 0) ? 64 : 0;   // px=-1 -> safe slot
                if (t == 7) v2 -= (m16 == 15) ? 64 : 0;  // px=128 -> safe slot
                a0 = *(const f16x8*)(xsb + v0);
                a1 = *(const f16x8*)(xsb + v1);
                a2 = *(const f16x8*)(xsb + v2);
                if (t == 0 && m16 == 0) a0 = zero8();
                if (t == 7 && m16 == 15) a2 = zero8();
            } else {
                a0 = hal[0];
                a1 = hal[1];
                a2 = hal[2];
                if (gvalid && t < 7) {  // prefetch next tile's halo trio
#pragma unroll
                    for (int kw = 0; kw < 3; ++kw)
                        hal[kw] = halo_ld(gp, (t + 1) * 16 + m16 + kw - 1);
                }
            }
            acc0 = __builtin_amdgcn_mfma_f32_16x16x32_f16(a0, bf[(kh * 3 + 0) * 2], acc0, 0, 0, 0);
            acc1 = __builtin_amdgcn_mfma_f32_16x16x32_f16(a0, bf[(kh * 3 + 0) * 2 + 1], acc1, 0, 0, 0);
            acc0 = __builtin_amdgcn_mfma_f32_16x16x32_f16(a1, bf[(kh * 3 + 1) * 2], acc0, 0, 0, 0);
            acc1 = __builtin_amdgcn_mfma_f32_16x16x32_f16(a1, bf[(kh * 3 + 1) * 2 + 1], acc1, 0, 0, 0);
            acc0 = __builtin_amdgcn_mfma_f32_16x16x32_f16(a2, bf[(kh * 3 + 2) * 2], acc0, 0, 0, 0);
            acc1 = __builtin_amdgcn_mfma_f32_16x16x32_f16(a2, bf[(kh * 3 + 2) * 2 + 1], acc1, 0, 0, 0);
        }

        // D layout: col = lane&15 (co), row = q*4 + r (pixel). Plain stores:
        // acc0+acc1 halves of each 128B line merge in L2.
        float* yp = ybase + t * 16 * COUT;
#pragma unroll
        for (int r = 0; r < 4; ++r) {
            yp[r * COUT] = acc0[r];
            yp[r * COUT + 16] = acc1[r];
        }

#pragma unroll
        for (int kw = 0; kw < 3; ++kw) va[kw] += 1024;  // +16 px
    }
}

extern "C" void kernel_launch(void* const* d_in, const int* in_sizes, int n_in,
                              void* d_out, int out_size, void* d_ws, size_t ws_size,
                              hipStream_t stream) {
    const float* X = (const float*)d_in[0];   // [32,128,128,32]
    const float* P = (const float*)d_in[1];   // [32,128]
    const float* Dw = (const float*)d_in[2];  // [128,9216]
    float* Y = (float*)d_out;                 // [32,128,128,32]
    (void)ws_size;

    unsigned short* WB = (unsigned short*)d_ws;  // 589824 B

    hipLaunchKernelGGL(hyper_gemm, dim3(144), dim3(256), 0, stream, P, Dw, WB);
    hipLaunchKernelGGL(conv_fused, dim3(512), dim3(512), 0, stream,
                       X, WB, Y);
}

// Round 3
// 132.779 us; speedup vs baseline: 1.1357x; 1.1357x over previous
//
#include <hip/hip_runtime.h>

// B=32, H=W=128, C_IN=C_OUT=32, 3x3 SAME conv, per-sample hypernet weights
// Wk[b] = (P[b] @ dense_w).reshape(3,3,32,32).
//
// R8: stream-pipelined conv (T14 async-STAGE split).
//  R7 post-mortem: conv 44us @ 2.6TB/s (31% peak), MfmaUtil 7% -> burst-phased
//  (all blocks: read-burst | barrier | compute+write-burst), nothing saturated.
//  NEW: block owns 16 rows (two 8-row groups), LDS 128KB contiguous
//  [16 rows][128 px][4 slots]. Pipeline: stage g0 -> issue g1 loads to regs ->
//  compute g0 (g1 HBM latency hides under MFMA+stores) -> cvt+write g1 ->
//  barrier -> compute g1. g1's top halo = LDS row 7 (contiguous array, the
//  (wave-1) addressing falls through) -> only wave0(g0)/wave7 touch global halo.
//  hyper: 288 blocks (was 144) -> half the serial latency-bound time.
// Verified swizzle math from R7 kept identical (absmax passed 0.25).

#define BATCH 32
#define HDIM 128
#define WDIM 128
#define CIN 32
#define COUT 32
#define PDIM 128
#define KCOLS 9216  // 3*3*32*32

typedef _Float16 f16x8 __attribute__((ext_vector_type(8)));
typedef float f32x4 __attribute__((ext_vector_type(4)));

__device__ __forceinline__ f16x8 zero8() {
    f16x8 z;
#pragma unroll
    for (int j = 0; j < 8; ++j) z[j] = (_Float16)0.f;
    return z;
}

// ---------------------------------------------------------------------------
// hyper_gemm: A = P @ dense_w -> f16, swizzled to MFMA B-frag layout
// WB[b][((kc*2 + co>>4)*64 + (ci>>3)*16 + (co&15))*8 + (ci&7)].
// 288 blocks x 256 thr: block = 64-col group (cg) x 16-batch half (bq);
// wave wv owns batches bq*16 + wv*4 .. +3. Dw col-panel read twice total
// (9.4 MB, L3-served). P via wave-uniform scalar loads.
// ---------------------------------------------------------------------------
__global__ __launch_bounds__(256) void hyper_gemm(const float* __restrict__ P,
                                                  const float* __restrict__ Dw,
                                                  unsigned short* __restrict__ WB) {
    const int tid = threadIdx.x;
    const int lane = tid & 63;
    const int cg = blockIdx.x % 144;
    const int bq = blockIdx.x / 144;  // 0..1
    const int col = cg * 64 + lane;
    const int b0 = __builtin_amdgcn_readfirstlane(bq * 16 + (tid >> 6) * 4);
    const float* pb = P + (size_t)b0 * PDIM;  // wave-uniform base -> s_load

    float acc[4];
#pragma unroll
    for (int j = 0; j < 4; ++j) acc[j] = 0.f;

#pragma unroll 2
    for (int mm = 0; mm < PDIM; mm += 16) {
        float d[16];
#pragma unroll
        for (int u = 0; u < 16; ++u) d[u] = Dw[(size_t)(mm + u) * KCOLS + col];
#pragma unroll
        for (int u = 0; u < 16; ++u) {
#pragma unroll
            for (int j = 0; j < 4; ++j) acc[j] += d[u] * pb[j * PDIM + mm + u];
        }
    }

    const int co = col & 31;
    const int k = col >> 5;
    const int kc = k >> 5;
    const int ci = k & 31;
    const int base =
        ((kc * 2 + (co >> 4)) * 64 + (ci >> 3) * 16 + (co & 15)) * 8 + (ci & 7);
#pragma unroll
    for (int j = 0; j < 4; ++j) {
        _Float16 v = (_Float16)acc[j];
        WB[(size_t)(b0 + j) * KCOLS + base] = __builtin_bit_cast(unsigned short, v);
    }
}

// ---------------------------------------------------------------------------
// conv_fused: implicit-GEMM conv, stream-pipelined.
// Grid 256 (XCD-swizzled), block = 512 thr / 8 waves, owns 16 rows (hg*16..).
// LDS 128 KB = [16 rows][128 px][4 x 16B slots], slot = q ^ (px>>1).
// Per group (8 rows, wave = 1 row): per tile t (16 px): 9 ds_read_b128
// A-frags + 18 MFMA 16x16x32_f16 + 8 stores. B-frags (18 f16x8 = 72 VGPR)
// loaded once from global WB (L2-hot). Halo: g0-wave0 / wave7 from f32
// global with 1-tile prefetch; g1-wave0 falls through to LDS row 7.
// launch_bounds(512,2): 1 block/CU (LDS-capped anyway), VGPR cap 256.
// ---------------------------------------------------------------------------
__device__ __forceinline__ f16x8 halo_ld(const f32x4* __restrict__ gp, int px) {
    const bool ok = (unsigned)px < 128u;
    const int p = ok ? px : 0;
    f32x4 lo = gp[p * 8];
    f32x4 hi = gp[p * 8 + 1];
    f16x8 o;
#pragma unroll
    for (int j = 0; j < 4; ++j) {
        o[j] = (_Float16)lo[j];
        o[4 + j] = (_Float16)hi[j];
    }
    if (!ok) o = zero8();
    return o;
}

// One 8-row group. TOPG: wave0 takes kh==0 from global halo (group 0);
// otherwise wave0's (wave-1) addressing falls through into the previous
// group's last LDS row. wave7 always takes kh==2 from the global path
// (validity via gvalid; invalid -> zeros).
template <bool TOPG>
__device__ __forceinline__ void compute_group(const char* xsb, int ldsbase,
                                              const f16x8* bf, float* ybase,
                                              const f32x4* gp, bool gvalid,
                                              int wave, int q, int m16) {
    f16x8 hal[3];
    if (gvalid) {
#pragma unroll
        for (int kw = 0; kw < 3; ++kw) hal[kw] = halo_ld(gp, m16 + kw - 1);
    } else {
#pragma unroll
        for (int kw = 0; kw < 3; ++kw) hal[kw] = zero8();
    }

    int va[3];
#pragma unroll
    for (int kw = 0; kw < 3; ++kw) {
        const int px = m16 + kw - 1;
        const int sl = (q ^ (px >> 1)) & 3;
        va[kw] = ldsbase + (wave - 1) * 8192 + px * 64 + sl * 16;
    }

#pragma unroll
    for (int t = 0; t < 8; ++t) {
        f32x4 acc0 = {0.f, 0.f, 0.f, 0.f};
        f32x4 acc1 = {0.f, 0.f, 0.f, 0.f};

#pragma unroll
        for (int kh = 0; kh < 3; ++kh) {
            f16x8 a0, a1, a2;
            const bool use_lds = (kh == 1) || (kh == 0 && (!TOPG || wave != 0)) ||
                                 (kh == 2 && wave != 7);
            if (use_lds) {
                int v0 = va[0] + kh * 8192;
                int v1 = va[1] + kh * 8192;
                int v2 = va[2] + kh * 8192;
                if (t == 0) v0 += (m16 == 0) ? 64 : 0;   // px=-1 -> safe slot
                if (t == 7) v2 -= (m16 == 15) ? 64 : 0;  // px=128 -> safe slot
                a0 = *(const f16x8*)(xsb + v0);
                a1 = *(const f16x8*)(xsb + v1);
                a2 = *(const f16x8*)(xsb + v2);
                if (t == 0 && m16 == 0) a0 = zero8();
                if (t == 7 && m16 == 15) a2 = zero8();
            } else {
                a0 = hal[0];
                a1 = hal[1];
                a2 = hal[2];
                if (gvalid && t < 7) {  // prefetch next tile's halo trio
#pragma unroll
                    for (int kw = 0; kw < 3; ++kw)
                        hal[kw] = halo_ld(gp, (t + 1) * 16 + m16 + kw - 1);
                }
            }
            acc0 = __builtin_amdgcn_mfma_f32_16x16x32_f16(a0, bf[(kh * 3 + 0) * 2], acc0, 0, 0, 0);
            acc1 = __builtin_amdgcn_mfma_f32_16x16x32_f16(a0, bf[(kh * 3 + 0) * 2 + 1], acc1, 0, 0, 0);
            acc0 = __builtin_amdgcn_mfma_f32_16x16x32_f16(a1, bf[(kh * 3 + 1) * 2], acc0, 0, 0, 0);
            acc1 = __builtin_amdgcn_mfma_f32_16x16x32_f16(a1, bf[(kh * 3 + 1) * 2 + 1], acc1, 0, 0, 0);
            acc0 = __builtin_amdgcn_mfma_f32_16x16x32_f16(a2, bf[(kh * 3 + 2) * 2], acc0, 0, 0, 0);
            acc1 = __builtin_amdgcn_mfma_f32_16x16x32_f16(a2, bf[(kh * 3 + 2) * 2 + 1], acc1, 0, 0, 0);
        }

        // D layout: col = lane&15 (co), row = q*4 + r (pixel). Plain stores:
        // acc0+acc1 halves of each 128B line merge in L2.
        float* yp = ybase + t * 16 * COUT;
#pragma unroll
        for (int r = 0; r < 4; ++r) {
            yp[r * COUT] = acc0[r];
            yp[r * COUT + 16] = acc1[r];
        }

#pragma unroll
        for (int kw = 0; kw < 3; ++kw) va[kw] += 1024;  // +16 px
    }
}

__global__ __launch_bounds__(512, 2) void conv_fused(const float* __restrict__ X,
                                                     const unsigned short* __restrict__ WB,
                                                     float* __restrict__ Y) {
    __shared__ f16x8 Xs[16 * 512];  // 128 KB: [row 0..15][px*4 + slot]
    const int tid = threadIdx.x;

    // XCD-aware swizzle: 256 % 8 == 0 -> simple bijective form.
    const int wg = blockIdx.x;
    const int id = (wg & 7) * 32 + (wg >> 3);
    const int b = id >> 3;
    const int hg = id & 7;
    const int r0 = hg * 16;

    const int wave = tid >> 6;
    const int lane = tid & 63;
    const int q = lane >> 4;    // ci octet
    const int m16 = lane & 15;  // pixel within tile

    // ---- B-fragments: direct global -> reg (18.4 KB/image, L2-hot) ----
    f16x8 bf[18];
    {
        const f16x8* wbp = (const f16x8*)(WB + (size_t)b * KCOLS);
#pragma unroll
        for (int i = 0; i < 18; ++i) bf[i] = wbp[i * 64 + lane];
    }

    // ---- staging geometry (thread covers one px octet across rows) ----
    const int px_s = tid >> 2;  // 0..127
    const int q_s = tid & 3;
    const int g_s = px_s * 4 + ((q_s ^ (px_s >> 1)) & 3);
    const float* xsrc = X + (((size_t)b * HDIM + r0) * WDIM + px_s) * CIN + q_s * 8;

    // ---- prologue: stage group-0 rows (0..7) ----
#pragma unroll
    for (int r = 0; r < 8; ++r) {
        f32x4 lo = *(const f32x4*)(xsrc + (size_t)r * WDIM * CIN);
        f32x4 hi = *(const f32x4*)(xsrc + (size_t)r * WDIM * CIN + 4);
        f16x8 o;
#pragma unroll
        for (int j = 0; j < 4; ++j) {
            o[j] = (_Float16)lo[j];
            o[4 + j] = (_Float16)hi[j];
        }
        Xs[r * 512 + g_s] = o;
    }

    // ---- issue group-1 loads (rows 8..15) into regs; latency hides under
    //      group-0 compute ----
    f32x4 R[16];
    const float* xsrc1 = xsrc + (size_t)8 * WDIM * CIN;
#pragma unroll
    for (int r = 0; r < 8; ++r) {
        R[2 * r] = *(const f32x4*)(xsrc1 + (size_t)r * WDIM * CIN);
        R[2 * r + 1] = *(const f32x4*)(xsrc1 + (size_t)r * WDIM * CIN + 4);
    }

    __syncthreads();

    const char* xsb = (const char*)Xs;
    const f32x4* Xb = (const f32x4*)X + (size_t)b * HDIM * (WDIM * CIN / 4);

    // ---- group 0: rows r0..r0+7 ----
    {
        const bool gvalid = (wave == 0) ? (hg != 0) : (wave == 7);
        const int grow = (wave == 0) ? (hg ? r0 - 1 : 0) : (r0 + 8);
        const f32x4* gp = Xb + (size_t)grow * (WDIM * CIN / 4) + q * 2;
        float* yb = Y + (((size_t)b * HDIM + r0 + wave) * WDIM + q * 4) * COUT + m16;
        compute_group<true>(xsb, 0, bf, yb, gp, gvalid, wave, q, m16);
    }

    // ---- write group-1 rows (compiler waits vmcnt on R use); disjoint LDS
    //      region from group-0 reads, so no barrier needed before writes ----
#pragma unroll
    for (int r = 0; r < 8; ++r) {
        f16x8 o;
#pragma unroll
        for (int j = 0; j < 4; ++j) {
            o[j] = (_Float16)R[2 * r][j];
            o[4 + j] = (_Float16)R[2 * r + 1][j];
        }
        Xs[(8 + r) * 512 + g_s] = o;
    }
    __syncthreads();

    // ---- group 1: rows r0+8..r0+15 (top halo = LDS row 7, falls through) ----
    {
        const bool gvalid = (wave == 7) && (hg != 7);
        const int grow = gvalid ? (r0 + 16) : 0;
        const f32x4* gp = Xb + (size_t)grow * (WDIM * CIN / 4) + q * 2;
        float* yb = Y + (((size_t)b * HDIM + r0 + 8 + wave) * WDIM + q * 4) * COUT + m16;
        compute_group<false>(xsb, 8 * 8192, bf, yb, gp, gvalid, wave, q, m16);
    }
}

extern "C" void kernel_launch(void* const* d_in, const int* in_sizes, int n_in,
                              void* d_out, int out_size, void* d_ws, size_t ws_size,
                              hipStream_t stream) {
    const float* X = (const float*)d_in[0];   // [32,128,128,32]
    const float* P = (const float*)d_in[1];   // [32,128]
    const float* Dw = (const float*)d_in[2];  // [128,9216]
    float* Y = (float*)d_out;                 // [32,128,128,32]
    (void)ws_size;

    unsigned short* WB = (unsigned short*)d_ws;  // 589824 B

    hipLaunchKernelGGL(hyper_gemm, dim3(288), dim3(256), 0, stream, P, Dw, WB);
    hipLaunchKernelGGL(conv_fused, dim3(256), dim3(512), 0, stream, X, WB, Y);
}